// Round 16
// baseline (801.959 us; speedup 1.0000x reference)
//
#include <hip/hip_runtime.h>
#include <math.h>

#define BN_EPS 1e-5f

namespace {

constexpr int Bb = 32;   // batch
constexpr int Cc = 512;  // channels
constexpr int Nn = 1024; // spatial (H*W)
constexpr int Ee = 1024; // embed

typedef __attribute__((ext_vector_type(8))) short short8;
typedef __attribute__((ext_vector_type(4))) float f32x4;
typedef __attribute__((ext_vector_type(4))) unsigned short ushort4_t;

struct bfpair { unsigned short h, l; };

__device__ __forceinline__ unsigned short bf16_rne(float v) {
  unsigned u = __builtin_bit_cast(unsigned, v);
  unsigned r = u + 0x7FFFu + ((u >> 16) & 1u);
  return (unsigned short)(r >> 16);
}
__device__ __forceinline__ float bf16_to_f(unsigned short h) {
  unsigned u = ((unsigned)h) << 16;
  return __builtin_bit_cast(float, u);
}
__device__ __forceinline__ bfpair split_bf(float v) {
  bfpair p;
  p.h = bf16_rne(v);
  p.l = bf16_rne(v - bf16_to_f(p.h));
  return p;
}

__device__ __forceinline__ void gll16(const void* g, void* l) {
  __builtin_amdgcn_global_load_lds(
      (const __attribute__((address_space(1))) void*)g,
      (__attribute__((address_space(3))) void*)l, 16, 0, 0);
}

// all three BN scale/shift pairs in one launch -> hdr[6][1024]
__global__ __launch_bounds__(256) void prep3(
    const float* __restrict__ qg, const float* __restrict__ qb,
    const float* __restrict__ qm, const float* __restrict__ qv,
    const float* __restrict__ kg, const float* __restrict__ kb,
    const float* __restrict__ km, const float* __restrict__ kv,
    const float* __restrict__ vg, const float* __restrict__ vb,
    const float* __restrict__ vm, const float* __restrict__ vv,
    float* __restrict__ hdr) {
  int i = blockIdx.x * blockDim.x + threadIdx.x;
  if (i < 1024) {
    float inv, sc;
    inv = rsqrtf(qv[i] + BN_EPS); sc = qg[i] * inv;
    hdr[i] = sc;          hdr[1024 + i] = qb[i] - qm[i] * sc;
    inv = rsqrtf(kv[i] + BN_EPS); sc = kg[i] * inv;
    hdr[2048 + i] = sc;   hdr[3072 + i] = kb[i] - km[i] * sc;
    inv = rsqrtf(vv[i] + BN_EPS); sc = vg[i] * inv;
    hdr[4096 + i] = sc;   hdr[5120 + i] = vb[i] - vm[i] * sc;
  }
}

// plain f32 -> hi/lo bf16 split (weights)
__global__ __launch_bounds__(256) void convert_w(
    const float* __restrict__ wsrc, unsigned short* __restrict__ wh,
    unsigned short* __restrict__ wl, long total4) {
  for (long i = (long)blockIdx.x * 256 + threadIdx.x; i < total4; i += (long)gridDim.x * 256) {
    float4 v = ((const float4*)wsrc)[i];
    bfpair p0 = split_bf(v.x), p1 = split_bf(v.y), p2 = split_bf(v.z), p3 = split_bf(v.w);
    ushort4_t hv, lv;
    hv.x = p0.h; hv.y = p1.h; hv.z = p2.h; hv.w = p3.h;
    lv.x = p0.l; lv.y = p1.l; lv.z = p2.l; lv.w = p3.l;
    *(ushort4_t*)&wh[i * 4] = hv;
    *(ushort4_t*)&wl[i * 4] = lv;
  }
}

// One x pass -> yq, yk (ws) and yv (d_out batch slots), all split hi/lo bf16.
__global__ __launch_bounds__(256) void convert_y3(
    const float* __restrict__ x, const float* __restrict__ hdr,
    unsigned short* __restrict__ yqh, unsigned short* __restrict__ yql,
    unsigned short* __restrict__ ykh, unsigned short* __restrict__ ykl,
    unsigned short* __restrict__ dout_us, long b0, long total4) {
  const float* sq = hdr;        const float* tq = hdr + 1024;
  const float* sk = hdr + 2048; const float* tk = hdr + 3072;
  const float* sv = hdr + 4096; const float* tv = hdr + 5120;
  for (long i = (long)blockIdx.x * 256 + threadIdx.x; i < total4; i += (long)gridDim.x * 256) {
    float4 v = ((const float4*)x)[i];
    int n4 = (int)(i & 255);
    float4 a, b;
    ushort4_t hv, lv;
    a = ((const float4*)sq)[n4]; b = ((const float4*)tq)[n4];
    {
      bfpair p0 = split_bf(fmaxf(fmaf(v.x, a.x, b.x), 0.f));
      bfpair p1 = split_bf(fmaxf(fmaf(v.y, a.y, b.y), 0.f));
      bfpair p2 = split_bf(fmaxf(fmaf(v.z, a.z, b.z), 0.f));
      bfpair p3 = split_bf(fmaxf(fmaf(v.w, a.w, b.w), 0.f));
      hv.x = p0.h; hv.y = p1.h; hv.z = p2.h; hv.w = p3.h;
      lv.x = p0.l; lv.y = p1.l; lv.z = p2.l; lv.w = p3.l;
      *(ushort4_t*)&yqh[i * 4] = hv; *(ushort4_t*)&yql[i * 4] = lv;
    }
    a = ((const float4*)sk)[n4]; b = ((const float4*)tk)[n4];
    {
      bfpair p0 = split_bf(fmaxf(fmaf(v.x, a.x, b.x), 0.f));
      bfpair p1 = split_bf(fmaxf(fmaf(v.y, a.y, b.y), 0.f));
      bfpair p2 = split_bf(fmaxf(fmaf(v.z, a.z, b.z), 0.f));
      bfpair p3 = split_bf(fmaxf(fmaf(v.w, a.w, b.w), 0.f));
      hv.x = p0.h; hv.y = p1.h; hv.z = p2.h; hv.w = p3.h;
      lv.x = p0.l; lv.y = p1.l; lv.z = p2.l; lv.w = p3.l;
      *(ushort4_t*)&ykh[i * 4] = hv; *(ushort4_t*)&ykl[i * 4] = lv;
    }
    a = ((const float4*)sv)[n4]; b = ((const float4*)tv)[n4];
    {
      bfpair p0 = split_bf(fmaxf(fmaf(v.x, a.x, b.x), 0.f));
      bfpair p1 = split_bf(fmaxf(fmaf(v.y, a.y, b.y), 0.f));
      bfpair p2 = split_bf(fmaxf(fmaf(v.z, a.z, b.z), 0.f));
      bfpair p3 = split_bf(fmaxf(fmaf(v.w, a.w, b.w), 0.f));
      hv.x = p0.h; hv.y = p1.h; hv.z = p2.h; hv.w = p3.h;
      lv.x = p0.l; lv.y = p1.l; lv.z = p2.l; lv.w = p3.l;
      long g = i >> 17;
      long local = i & 131071;
      unsigned short* slot = dout_us + (b0 + g) * 1048576L;
      *(ushort4_t*)&slot[local * 4] = hv;
      *(ushort4_t*)&slot[524288 + local * 4] = lv;
    }
  }
}

#define MFMA16 __builtin_amdgcn_mfma_f32_16x16x32_bf16

// ---------------------------------------------------------------------------
// TRIPLE-BUFFERED split-bf16 NT GEMM, BM=128 x BN=256, 512 threads / 8 waves
// (2x4, wave tile 64x64), BK=32, mfma 16x16x32.
// BMODE 0: acc += Ah*Bh + Ah*Bl + Al*Bh   (LDS 144 KiB: 3 bufs x 48 KiB)
// BMODE 1: acc += Ah*Bh + Al*Bh  (PV: B = P_hi only; LDS 96 KiB)
// r16 schedule: 3 buffers kill the mid-tile fence entirely.
//   prologue STAGE(0->buf0), STAGE(1->buf1)
//   per tile t: vmcnt(LPS) counted [tile t landed; t+1 in flight; ~2 tiles of
//   flight time >> HBM latency so the wait is cheap] -> s_barrier ->
//   STAGE(t+2 -> buf[(t+2)%3]) -> ds_reads(buf[t%3]) -> MFMA (compiler
//   partial-lgkm interleave).  Readers(t), in-flight(t+1), writers(t+2) are
//   three distinct buffers -> no lgkm fence, ONE barrier per tile.
//   Safety: wave past tile-t barrier has issued all tile-(t-1) MFMAs whose
//   operand interlocks prove its buf[(t+2)%3] reads completed; per-wave
//   counted vmcnt before the barrier makes tile-t gll16 writes visible.
// Chunk-XOR LDS swizzle (validated r5-r15: 0 conflicts).
// B operand selected by m0 (>= msel -> B1) for stacked-[Wq;Wk] projection.
// ---------------------------------------------------------------------------
template<bool SPLIT, bool MFIRST, int BMODE>
__global__ __launch_bounds__(512, 2) void gemm3p(
    const unsigned short* __restrict__ Ah, const unsigned short* __restrict__ Al,
    long ldA, long bsA,
    const unsigned short* __restrict__ Bh0, const unsigned short* __restrict__ Bl0,
    const unsigned short* __restrict__ Bh1, const unsigned short* __restrict__ Bl1,
    int msel, long ldB, long bsB,
    float* __restrict__ Cf, unsigned short* __restrict__ Chi, unsigned short* __restrict__ Clo,
    long ldC, long bsC, int K, float alpha, int g0, int g1) {
  constexpr int WH = 64;                    // wave tile rows
  constexpr int NB = (BMODE == 0) ? 2 : 1;  // B planes staged
  __shared__ unsigned short sA[3][2][128][32];
  __shared__ unsigned short sB[3][NB][256][32];

  const int nb = gridDim.x;
  int f = blockIdx.x;
  if ((nb & 7) == 0) f = (f & 7) * (nb >> 3) + (f >> 3);  // XCD-chunked swizzle
  const int i0 = f % g0, i1 = (f / g0) % g1;
  const long zb = f / (g0 * g1);
  const int m0 = (MFIRST ? i0 : i1) * 128;
  const int n0 = (MFIRST ? i1 : i0) * 256;

  const int t = threadIdx.x, lane = t & 63, w = t >> 6;  // w: 0..7
  const int wr = w >> 2, wc = w & 3;                     // wave tile (wr, wc)
  const int sr  = lane >> 2;
  const int skc = (((lane & 3) ^ ((lane >> 3) & 3)) * 8);      // permuted global col
  const int fr = lane & 15;
  const int kq = ((((lane >> 4) & 3) ^ ((fr >> 1) & 3)) * 8);  // swizzled read col

  const unsigned short* Bh = (m0 >= msel) ? Bh1 : Bh0;
  const unsigned short* Bl = (m0 >= msel) ? Bl1 : Bl0;
  if (BMODE == 1) Bl = Bh;  // unused, keep pointer valid

  // staging pointers: wave w stages A rows (w&3)*32..+31 of plane (w>>2),
  // and B rows w*32..+31 of each staged plane.
  const int aw = w & 3, ahl = w >> 2;
  const unsigned short* a0 =
      (ahl ? Al : Ah) + zb * bsA + (long)(m0 + aw * 32 + sr) * ldA + skc;
  const unsigned short* b0 = Bh + zb * bsB + (long)(n0 + w * 32 + sr) * ldB + skc;
  const unsigned short* b1 = Bl + zb * bsB + (long)(n0 + w * 32 + sr) * ldB + skc;
  const long a16 = 16 * ldA, b16 = 16 * ldB;

  // loads/thread/STAGE: BMODE0 -> 6, BMODE1 -> 4  (vmcnt depends on this)
  auto STAGE = [&](int buf) {
    gll16(a0, &sA[buf][ahl][aw * 32][0]);
    gll16(a0 + a16, &sA[buf][ahl][aw * 32 + 16][0]);
    a0 += 32;
    gll16(b0, &sB[buf][0][w * 32][0]);  gll16(b0 + b16, &sB[buf][0][w * 32 + 16][0]);
    b0 += 32;
    if constexpr (BMODE == 0) {
      gll16(b1, &sB[buf][NB - 1][w * 32][0]);
      gll16(b1 + b16, &sB[buf][NB - 1][w * 32 + 16][0]);
      b1 += 32;
    }
  };

  f32x4 acc[4][4] = {};
  const int nt = K >> 5;

  STAGE(0);
  STAGE(1);

  for (int it = 0; it < nt; ++it) {
    const int cur = it % 3;
    if (it + 1 < nt) {
      if constexpr (BMODE == 0) asm volatile("s_waitcnt vmcnt(6)" ::: "memory");
      else                      asm volatile("s_waitcnt vmcnt(4)" ::: "memory");
    } else {
      asm volatile("s_waitcnt vmcnt(0)" ::: "memory");
    }
    asm volatile("s_barrier" ::: "memory");   // buf[cur] staged & visible;
                                              // buf[(it+2)%3] fully consumed
    if (it + 2 < nt) STAGE((it + 2) % 3);     // fence-free (3rd buffer)

    short8 bh[4], bl[4], ah[4], al[4];
#pragma unroll
    for (int j = 0; j < 4; ++j) {
      bh[j] = *(const short8*)&sB[cur][0][wc * 64 + j * 16 + fr][kq];
      if (BMODE == 0)
        bl[j] = *(const short8*)&sB[cur][NB - 1][wc * 64 + j * 16 + fr][kq];
    }
#pragma unroll
    for (int i = 0; i < 4; ++i) {
      ah[i] = *(const short8*)&sA[cur][0][wr * WH + i * 16 + fr][kq];
      al[i] = *(const short8*)&sA[cur][1][wr * WH + i * 16 + fr][kq];
    }
    __builtin_amdgcn_s_setprio(1);
#pragma unroll
    for (int i = 0; i < 4; ++i)
#pragma unroll
      for (int j = 0; j < 4; ++j) {
        acc[i][j] = MFMA16(ah[i], bh[j], acc[i][j], 0, 0, 0);
        if (BMODE == 0) acc[i][j] = MFMA16(ah[i], bl[j], acc[i][j], 0, 0, 0);
        acc[i][j] = MFMA16(al[i], bh[j], acc[i][j], 0, 0, 0);
      }
    __builtin_amdgcn_s_setprio(0);
  }

  // epilogue: C/D layout col = lane&15, row = (lane>>4)*4 + reg  [verified m89/m91]
  const int rb = ((lane >> 4) & 3) * 4;
#pragma unroll
  for (int i = 0; i < 4; ++i)
#pragma unroll
    for (int j = 0; j < 4; ++j) {
      long col = n0 + wc * 64 + j * 16 + fr;
#pragma unroll
      for (int v = 0; v < 4; ++v) {
        long row = m0 + wr * WH + i * 16 + rb + v;
        float val = acc[i][j][v] * alpha;
        long idx = zb * bsC + row * ldC + col;
        if (SPLIT) {
          bfpair p = split_bf(val);
          Chi[idx] = p.h;
          Clo[idx] = p.l;
        } else {
          Cf[idx] = val;
        }
      }
    }
}

// softmax over rows of 1024 f32; writes P_hi bf16 into first 1024 ushorts of
// each 4KB row (P_lo dropped -- consumed by BMODE=1 PV GEMM).
__global__ __launch_bounds__(256) void softmax_rows(float* __restrict__ S) {
  long row = blockIdx.x;
  float* p = S + row * 1024;
  int t = threadIdx.x;
  float4 v = *(float4*)(p + 4 * t);
  float mx = fmaxf(fmaxf(v.x, v.y), fmaxf(v.z, v.w));
#pragma unroll
  for (int i = 1; i < 64; i <<= 1) mx = fmaxf(mx, __shfl_xor(mx, i));
  __shared__ float redm[4];
  __shared__ float reds[4];
  int wave = t >> 6, lane = t & 63;
  if (lane == 0) redm[wave] = mx;
  __syncthreads();
  mx = fmaxf(fmaxf(redm[0], redm[1]), fmaxf(redm[2], redm[3]));
  float e0 = expf(v.x - mx), e1 = expf(v.y - mx);
  float e2 = expf(v.z - mx), e3 = expf(v.w - mx);
  float sum = (e0 + e1) + (e2 + e3);
#pragma unroll
  for (int i = 1; i < 64; i <<= 1) sum += __shfl_xor(sum, i);
  if (lane == 0) reds[wave] = sum;
  __syncthreads();
  sum = (reds[0] + reds[1]) + (reds[2] + reds[3]);
  float inv = 1.0f / sum;
  ushort4_t hv;
  hv.x = bf16_rne(e0 * inv);
  hv.y = bf16_rne(e1 * inv);
  hv.z = bf16_rne(e2 * inv);
  hv.w = bf16_rne(e3 * inv);
  unsigned short* ph = (unsigned short*)p;
  *(ushort4_t*)&ph[4 * t] = hv;
}

}  // namespace

extern "C" void kernel_launch(void* const* d_in, const int* in_sizes, int n_in,
                              void* d_out, int out_size, void* d_ws, size_t ws_size,
                              hipStream_t stream) {
  const float* x  = (const float*)d_in[0];
  const float* qg = (const float*)d_in[1];
  const float* qb = (const float*)d_in[2];
  const float* qm = (const float*)d_in[3];
  const float* qv = (const float*)d_in[4];
  const float* kg = (const float*)d_in[5];
  const float* kb = (const float*)d_in[6];
  const float* km = (const float*)d_in[7];
  const float* kv = (const float*)d_in[8];
  const float* vg = (const float*)d_in[9];
  const float* vb = (const float*)d_in[10];
  const float* vm = (const float*)d_in[11];
  const float* vv = (const float*)d_in[12];
  const float* Wq = (const float*)d_in[13];
  const float* Wk = (const float*)d_in[14];
  const float* Wv = (const float*)d_in[15];
  const float* Wp = (const float*)d_in[16];

  // ---- workspace (r9 layout) ----
  const size_t wFix = 65536 + 16UL * 1024 * 1024;
  const size_t perB = 12UL * 1024 * 1024;
  int G = 32;
  while (G > 1 && wFix + (size_t)G * perB > ws_size) G >>= 1;

  char* ws = (char*)d_ws;
  float* hdr = (float*)ws;

  const long WE = 1024L * 1024;
  unsigned short* WQKh = (unsigned short*)(ws + 65536);  // [2048][1024]
  unsigned short* WQKl = WQKh + 2 * WE;
  unsigned short* Wvh  = WQKl + 2 * WE;
  unsigned short* Wvl  = Wvh + WE;
  unsigned short* Wph  = Wvl + WE;
  unsigned short* Wpl  = Wph + WE;

  const long YB = 524288;
  unsigned short* yqh = Wpl + WE;
  unsigned short* yql = yqh + (long)G * YB;
  unsigned short* ykh = yql + (long)G * YB;
  unsigned short* ykl = ykh + (long)G * YB;
  const long QKBS = 1048576;
  unsigned short* QKh = ykl + (long)G * YB;
  unsigned short* QKl = QKh + (long)G * QKBS;
  float* S = (float*)(QKl + (long)G * QKBS);

  unsigned short* dout_us = (unsigned short*)d_out;

  dim3 blk(256);
  const int BIG = 1 << 30;

  prep3<<<dim3(4), blk, 0, stream>>>(qg, qb, qm, qv, kg, kb, km, kv, vg, vb, vm, vv, hdr);

  const long W4 = WE / 4;
  convert_w<<<dim3(1024), blk, 0, stream>>>(Wq, WQKh, WQKl, W4);
  convert_w<<<dim3(1024), blk, 0, stream>>>(Wk, WQKh + WE, WQKl + WE, W4);
  convert_w<<<dim3(1024), blk, 0, stream>>>(Wv, Wvh, Wvl, W4);
  convert_w<<<dim3(1024), blk, 0, stream>>>(Wp, Wph, Wpl, W4);

  for (int b0 = 0; b0 < Bb; b0 += G) {
    const float* xg = x + (size_t)b0 * Cc * Nn;

    // 1) BN+ReLU+split: yq,yk -> ws; yv -> d_out slots
    convert_y3<<<dim3(2048), blk, 0, stream>>>(
        xg, hdr, yqh, yql, ykh, ykl, dout_us, b0, (long)G * 131072);

    // 2) [Q;K] = [Wq;Wk] x y: M=2048, N=512, K=1024; m-fastest (y-panel reuse)
    gemm3p<true, true, 0><<<dim3(16 * 2 * G), dim3(512), 0, stream>>>(
        WQKh, WQKl, Nn, 0L,
        yqh, yql, ykh, ykl, 1024, Nn, YB,
        nullptr, QKh, QKl, Cc, QKBS, Nn, 1.0f, 16, 2);

    // 3) S = Q K^T / 32: M=1024, N=1024, K=512
    gemm3p<false, false, 0><<<dim3(4 * 8 * G), dim3(512), 0, stream>>>(
        QKh, QKl, Cc, QKBS,
        QKh + 524288, QKl + 524288, nullptr, nullptr, BIG, Cc, QKBS,
        S, nullptr, nullptr, Ee, 1048576L, Cc, 0.03125f, 4, 8);

    // 4) softmax rows -> P_hi packed in S (lo dropped)
    softmax_rows<<<dim3(G * Ee), blk, 0, stream>>>(S);

    // 5) Vt[c][e] = sum_n yv[c][n] Wv[e][n]: M=512, N=1024, K=1024; 3-term
    gemm3p<true, false, 0><<<dim3(4 * 4 * G), dim3(512), 0, stream>>>(
        dout_us + (long)b0 * 1048576, dout_us + (long)b0 * 1048576 + 524288, Nn, 1048576L,
        Wvh, Wvl, nullptr, nullptr, BIG, Nn, 0L,
        nullptr, yqh, yql, Ee, YB, Nn, 1.0f, 4, 4);

    // 6) Ot[c][e] = sum_f Vt[c][f] P[e][f]: M=512, N=1024, K=1024;
    //    B = P_hi only (BMODE=1, 2-term)
    gemm3p<true, false, 1><<<dim3(4 * 4 * G), dim3(512), 0, stream>>>(
        yqh, yql, Ee, YB,
        (unsigned short*)S, nullptr, nullptr, nullptr, BIG,
        2L * Ee, 2097152L,
        nullptr, QKh, QKl, Ee, QKBS, Ee, 1.0f, 4, 4);

    // 7) out[c][n] = sum_e Ot[c][e] Wp[n][e]: M=512, N=1024, K=1024; f32 out
    gemm3p<false, false, 0><<<dim3(4 * 4 * G), dim3(512), 0, stream>>>(
        QKh, QKl, Ee, QKBS,
        Wph, Wpl, nullptr, nullptr, BIG, Ee, 0L,
        (float*)d_out + (size_t)b0 * Cc * Nn, nullptr, nullptr,
        Nn, (long)Cc * Nn, Ee, 1.0f, 4, 4);
  }
}

// Round 17
// 701.307 us; speedup vs baseline: 1.1435x; 1.1435x over previous
//
#include <hip/hip_runtime.h>
#include <math.h>

#define BN_EPS 1e-5f

namespace {

constexpr int Bb = 32;   // batch
constexpr int Cc = 512;  // channels
constexpr int Nn = 1024; // spatial (H*W)
constexpr int Ee = 1024; // embed

typedef __attribute__((ext_vector_type(8))) short short8;
typedef __attribute__((ext_vector_type(4))) float f32x4;
typedef __attribute__((ext_vector_type(4))) unsigned short ushort4_t;

struct bfpair { unsigned short h, l; };

__device__ __forceinline__ unsigned short bf16_rne(float v) {
  unsigned u = __builtin_bit_cast(unsigned, v);
  unsigned r = u + 0x7FFFu + ((u >> 16) & 1u);
  return (unsigned short)(r >> 16);
}
__device__ __forceinline__ float bf16_to_f(unsigned short h) {
  unsigned u = ((unsigned)h) << 16;
  return __builtin_bit_cast(float, u);
}
__device__ __forceinline__ bfpair split_bf(float v) {
  bfpair p;
  p.h = bf16_rne(v);
  p.l = bf16_rne(v - bf16_to_f(p.h));
  return p;
}

__device__ __forceinline__ void gll16(const void* g, void* l) {
  __builtin_amdgcn_global_load_lds(
      (const __attribute__((address_space(1))) void*)g,
      (__attribute__((address_space(3))) void*)l, 16, 0, 0);
}

// all three BN scale/shift pairs in one launch -> hdr[6][1024]
__global__ __launch_bounds__(256) void prep3(
    const float* __restrict__ qg, const float* __restrict__ qb,
    const float* __restrict__ qm, const float* __restrict__ qv,
    const float* __restrict__ kg, const float* __restrict__ kb,
    const float* __restrict__ km, const float* __restrict__ kv,
    const float* __restrict__ vg, const float* __restrict__ vb,
    const float* __restrict__ vm, const float* __restrict__ vv,
    float* __restrict__ hdr) {
  int i = blockIdx.x * blockDim.x + threadIdx.x;
  if (i < 1024) {
    float inv, sc;
    inv = rsqrtf(qv[i] + BN_EPS); sc = qg[i] * inv;
    hdr[i] = sc;          hdr[1024 + i] = qb[i] - qm[i] * sc;
    inv = rsqrtf(kv[i] + BN_EPS); sc = kg[i] * inv;
    hdr[2048 + i] = sc;   hdr[3072 + i] = kb[i] - km[i] * sc;
    inv = rsqrtf(vv[i] + BN_EPS); sc = vg[i] * inv;
    hdr[4096 + i] = sc;   hdr[5120 + i] = vb[i] - vm[i] * sc;
  }
}

// plain f32 -> hi/lo bf16 split (weights)
__global__ __launch_bounds__(256) void convert_w(
    const float* __restrict__ wsrc, unsigned short* __restrict__ wh,
    unsigned short* __restrict__ wl, long total4) {
  for (long i = (long)blockIdx.x * 256 + threadIdx.x; i < total4; i += (long)gridDim.x * 256) {
    float4 v = ((const float4*)wsrc)[i];
    bfpair p0 = split_bf(v.x), p1 = split_bf(v.y), p2 = split_bf(v.z), p3 = split_bf(v.w);
    ushort4_t hv, lv;
    hv.x = p0.h; hv.y = p1.h; hv.z = p2.h; hv.w = p3.h;
    lv.x = p0.l; lv.y = p1.l; lv.z = p2.l; lv.w = p3.l;
    *(ushort4_t*)&wh[i * 4] = hv;
    *(ushort4_t*)&wl[i * 4] = lv;
  }
}

// One x pass -> yq, yk (ws) and yv (d_out batch slots), all split hi/lo bf16.
__global__ __launch_bounds__(256) void convert_y3(
    const float* __restrict__ x, const float* __restrict__ hdr,
    unsigned short* __restrict__ yqh, unsigned short* __restrict__ yql,
    unsigned short* __restrict__ ykh, unsigned short* __restrict__ ykl,
    unsigned short* __restrict__ dout_us, long b0, long total4) {
  const float* sq = hdr;        const float* tq = hdr + 1024;
  const float* sk = hdr + 2048; const float* tk = hdr + 3072;
  const float* sv = hdr + 4096; const float* tv = hdr + 5120;
  for (long i = (long)blockIdx.x * 256 + threadIdx.x; i < total4; i += (long)gridDim.x * 256) {
    float4 v = ((const float4*)x)[i];
    int n4 = (int)(i & 255);
    float4 a, b;
    ushort4_t hv, lv;
    a = ((const float4*)sq)[n4]; b = ((const float4*)tq)[n4];
    {
      bfpair p0 = split_bf(fmaxf(fmaf(v.x, a.x, b.x), 0.f));
      bfpair p1 = split_bf(fmaxf(fmaf(v.y, a.y, b.y), 0.f));
      bfpair p2 = split_bf(fmaxf(fmaf(v.z, a.z, b.z), 0.f));
      bfpair p3 = split_bf(fmaxf(fmaf(v.w, a.w, b.w), 0.f));
      hv.x = p0.h; hv.y = p1.h; hv.z = p2.h; hv.w = p3.h;
      lv.x = p0.l; lv.y = p1.l; lv.z = p2.l; lv.w = p3.l;
      *(ushort4_t*)&yqh[i * 4] = hv; *(ushort4_t*)&yql[i * 4] = lv;
    }
    a = ((const float4*)sk)[n4]; b = ((const float4*)tk)[n4];
    {
      bfpair p0 = split_bf(fmaxf(fmaf(v.x, a.x, b.x), 0.f));
      bfpair p1 = split_bf(fmaxf(fmaf(v.y, a.y, b.y), 0.f));
      bfpair p2 = split_bf(fmaxf(fmaf(v.z, a.z, b.z), 0.f));
      bfpair p3 = split_bf(fmaxf(fmaf(v.w, a.w, b.w), 0.f));
      hv.x = p0.h; hv.y = p1.h; hv.z = p2.h; hv.w = p3.h;
      lv.x = p0.l; lv.y = p1.l; lv.z = p2.l; lv.w = p3.l;
      *(ushort4_t*)&ykh[i * 4] = hv; *(ushort4_t*)&ykl[i * 4] = lv;
    }
    a = ((const float4*)sv)[n4]; b = ((const float4*)tv)[n4];
    {
      bfpair p0 = split_bf(fmaxf(fmaf(v.x, a.x, b.x), 0.f));
      bfpair p1 = split_bf(fmaxf(fmaf(v.y, a.y, b.y), 0.f));
      bfpair p2 = split_bf(fmaxf(fmaf(v.z, a.z, b.z), 0.f));
      bfpair p3 = split_bf(fmaxf(fmaf(v.w, a.w, b.w), 0.f));
      hv.x = p0.h; hv.y = p1.h; hv.z = p2.h; hv.w = p3.h;
      lv.x = p0.l; lv.y = p1.l; lv.z = p2.l; lv.w = p3.l;
      long g = i >> 17;
      long local = i & 131071;
      unsigned short* slot = dout_us + (b0 + g) * 1048576L;
      *(ushort4_t*)&slot[local * 4] = hv;
      *(ushort4_t*)&slot[524288 + local * 4] = lv;
    }
  }
}

#define MFMA16 __builtin_amdgcn_mfma_f32_16x16x32_bf16

// ---------------------------------------------------------------------------
// Pipelined split-bf16 NT GEMM (r9 schedule, validated champion; r15 config).
// 512 threads / 8 waves (2x4), BK=32, mfma 16x16x32.
// BMODE 0: acc += Ah*Bh + Ah*Bl + Al*Bh  (3-term, full split B)
// BMODE 1: acc += Ah*Bh + Al*Bh          (B hi-only; PV: B = P in [0,1],
//          dropped P_lo residual is sign-alternating -> incoherent, safe)
// BM=256: wave tile 128x64, LDS 128 KiB dbuf, 8 gll16/thread/stage, vmcnt(8).
// BM=128 BMODE0: 96 KiB, 6 loads, vmcnt(6).  BM=128 BMODE1: 64 KiB, 4 loads,
//          vmcnt(4) -> 2 blocks/CU.
// Per tile: vmcnt(N) counted -> barrier -> frag reads -> [BM256: MFMA half1
// -> reads half2] -> lgkmcnt(0) -> barrier -> STAGE(t+2) -> MFMA rest.
// Chunk-XOR LDS swizzle (validated r5-r15: 0 conflicts).
// B operand selected by m0 (>= msel -> B1) for stacked-[Wq;Wk] projection.
// NOTE: 7 schedule variants (1-deep, 3-buf, phase-split x2, shape x2, fence
// reorder) all regressed vs this template -- do not perturb sync structure.
// ---------------------------------------------------------------------------
template<bool SPLIT, bool MFIRST, int BM, int BMODE>
__global__ __launch_bounds__(512, 2) void gemm3p(
    const unsigned short* __restrict__ Ah, const unsigned short* __restrict__ Al,
    long ldA, long bsA,
    const unsigned short* __restrict__ Bh0, const unsigned short* __restrict__ Bl0,
    const unsigned short* __restrict__ Bh1, const unsigned short* __restrict__ Bl1,
    int msel, long ldB, long bsB,
    float* __restrict__ Cf, unsigned short* __restrict__ Chi, unsigned short* __restrict__ Clo,
    long ldC, long bsC, int K, float alpha, int g0, int g1) {
  constexpr int WH = BM / 2;   // wave tile rows
  constexpr int AF = WH / 16;  // A fragments per wave (8 or 4)
  constexpr int NB = (BMODE == 0) ? 2 : 1;  // B planes staged
  __shared__ unsigned short sA[2][2][BM][32];
  __shared__ unsigned short sB[2][NB][256][32];

  const int nb = gridDim.x;
  int f = blockIdx.x;
  if ((nb & 7) == 0) f = (f & 7) * (nb >> 3) + (f >> 3);  // XCD-chunked swizzle
  const int i0 = f % g0, i1 = (f / g0) % g1;
  const long zb = f / (g0 * g1);
  const int m0 = (MFIRST ? i0 : i1) * BM;
  const int n0 = (MFIRST ? i1 : i0) * 256;

  const int t = threadIdx.x, lane = t & 63, w = t >> 6;  // w: 0..7
  const int wr = w >> 2, wc = w & 3;                     // wave tile (wr, wc)
  const int sr  = lane >> 2;
  const int skc = (((lane & 3) ^ ((lane >> 3) & 3)) * 8);      // permuted global col
  const int fr = lane & 15;
  const int kq = ((((lane >> 4) & 3) ^ ((fr >> 1) & 3)) * 8);  // swizzled read col

  const unsigned short* Bh = (m0 >= msel) ? Bh1 : Bh0;
  const unsigned short* Bl = (m0 >= msel) ? Bl1 : Bl0;
  if (BMODE == 1) Bl = Bh;  // unused, keep pointer valid

  // staging pointers
  const int aw = w & 3, ahl = w >> 2;  // BM==128 mapping
  const unsigned short* a0;
  const unsigned short* a1 = nullptr;
  if (BM == 256) {
    a0 = Ah + zb * bsA + (long)(m0 + w * 32 + sr) * ldA + skc;
    a1 = Al + zb * bsA + (long)(m0 + w * 32 + sr) * ldA + skc;
  } else {
    a0 = (ahl ? Al : Ah) + zb * bsA + (long)(m0 + aw * 32 + sr) * ldA + skc;
  }
  const unsigned short* b0 = Bh + zb * bsB + (long)(n0 + w * 32 + sr) * ldB + skc;
  const unsigned short* b1 = Bl + zb * bsB + (long)(n0 + w * 32 + sr) * ldB + skc;
  const long a16 = 16 * ldA, b16 = 16 * ldB;

  // loads/thread/STAGE: BM256 -> 8, BM128 BMODE0 -> 6, BM128 BMODE1 -> 4
  auto STAGE = [&](int buf) {
    if constexpr (BM == 256) {
      gll16(a0, &sA[buf][0][w * 32][0]);  gll16(a0 + a16, &sA[buf][0][w * 32 + 16][0]);
      gll16(a1, &sA[buf][1][w * 32][0]);  gll16(a1 + a16, &sA[buf][1][w * 32 + 16][0]);
      a0 += 32; a1 += 32;
    } else {
      gll16(a0, &sA[buf][ahl][aw * 32][0]);
      gll16(a0 + a16, &sA[buf][ahl][aw * 32 + 16][0]);
      a0 += 32;
    }
    gll16(b0, &sB[buf][0][w * 32][0]);  gll16(b0 + b16, &sB[buf][0][w * 32 + 16][0]);
    b0 += 32;
    if constexpr (BMODE == 0) {
      gll16(b1, &sB[buf][NB - 1][w * 32][0]);
      gll16(b1 + b16, &sB[buf][NB - 1][w * 32 + 16][0]);
      b1 += 32;
    }
  };

  f32x4 acc[AF][4] = {};
  const int nt = K >> 5;

  STAGE(0);
  STAGE(1);
  int cur = 0;

  for (int it = 0; it < nt; ++it) {
    if (it + 1 < nt) {
      if constexpr (BM == 256)      asm volatile("s_waitcnt vmcnt(8)" ::: "memory");
      else if constexpr (BMODE == 0) asm volatile("s_waitcnt vmcnt(6)" ::: "memory");
      else                           asm volatile("s_waitcnt vmcnt(4)" ::: "memory");
    } else {
      asm volatile("s_waitcnt vmcnt(0)" ::: "memory");
    }
    asm volatile("s_barrier" ::: "memory");   // buf[cur] staged by all waves

    short8 bh[4], bl[4], ah[4], al[4];
#pragma unroll
    for (int j = 0; j < 4; ++j) {
      bh[j] = *(const short8*)&sB[cur][0][wc * 64 + j * 16 + fr][kq];
      if (BMODE == 0)
        bl[j] = *(const short8*)&sB[cur][NB - 1][wc * 64 + j * 16 + fr][kq];
    }
#pragma unroll
    for (int i = 0; i < 4; ++i) {
      ah[i] = *(const short8*)&sA[cur][0][wr * WH + i * 16 + fr][kq];
      al[i] = *(const short8*)&sA[cur][1][wr * WH + i * 16 + fr][kq];
    }

    if constexpr (BM == 256) {
      __builtin_amdgcn_s_setprio(1);
#pragma unroll
      for (int i = 0; i < 4; ++i)
#pragma unroll
        for (int j = 0; j < 4; ++j) {
          acc[i][j] = MFMA16(ah[i], bh[j], acc[i][j], 0, 0, 0);
          if (BMODE == 0) acc[i][j] = MFMA16(ah[i], bl[j], acc[i][j], 0, 0, 0);
          acc[i][j] = MFMA16(al[i], bh[j], acc[i][j], 0, 0, 0);
        }
      __builtin_amdgcn_s_setprio(0);
      // A half 2 (reuse regs)
#pragma unroll
      for (int i = 0; i < 4; ++i) {
        ah[i] = *(const short8*)&sA[cur][0][wr * WH + (i + 4) * 16 + fr][kq];
        al[i] = *(const short8*)&sA[cur][1][wr * WH + (i + 4) * 16 + fr][kq];
      }
      asm volatile("s_waitcnt lgkmcnt(0)" ::: "memory");
      asm volatile("s_barrier" ::: "memory");
      if (it + 2 < nt) STAGE(cur);
      __builtin_amdgcn_s_setprio(1);
#pragma unroll
      for (int i = 0; i < 4; ++i)
#pragma unroll
        for (int j = 0; j < 4; ++j) {
          acc[i + 4][j] = MFMA16(ah[i], bh[j], acc[i + 4][j], 0, 0, 0);
          if (BMODE == 0) acc[i + 4][j] = MFMA16(ah[i], bl[j], acc[i + 4][j], 0, 0, 0);
          acc[i + 4][j] = MFMA16(al[i], bh[j], acc[i + 4][j], 0, 0, 0);
        }
      __builtin_amdgcn_s_setprio(0);
    } else {
      asm volatile("s_waitcnt lgkmcnt(0)" ::: "memory");
      asm volatile("s_barrier" ::: "memory");
      if (it + 2 < nt) STAGE(cur);
      __builtin_amdgcn_s_setprio(1);
#pragma unroll
      for (int i = 0; i < 4; ++i)
#pragma unroll
        for (int j = 0; j < 4; ++j) {
          acc[i][j] = MFMA16(ah[i], bh[j], acc[i][j], 0, 0, 0);
          if (BMODE == 0) acc[i][j] = MFMA16(ah[i], bl[j], acc[i][j], 0, 0, 0);
          acc[i][j] = MFMA16(al[i], bh[j], acc[i][j], 0, 0, 0);
        }
      __builtin_amdgcn_s_setprio(0);
    }
    cur ^= 1;
  }

  // epilogue: C/D layout col = lane&15, row = (lane>>4)*4 + reg  [verified m89/m91]
  const int rb = ((lane >> 4) & 3) * 4;
#pragma unroll
  for (int i = 0; i < AF; ++i)
#pragma unroll
    for (int j = 0; j < 4; ++j) {
      long col = n0 + wc * 64 + j * 16 + fr;
#pragma unroll
      for (int v = 0; v < 4; ++v) {
        long row = m0 + wr * WH + i * 16 + rb + v;
        float val = acc[i][j][v] * alpha;
        long idx = zb * bsC + row * ldC + col;
        if (SPLIT) {
          bfpair p = split_bf(val);
          Chi[idx] = p.h;
          Clo[idx] = p.l;
        } else {
          Cf[idx] = val;
        }
      }
    }
}

// softmax over rows of 1024 f32; writes P_hi bf16 into first 1024 ushorts of
// each 4KB row (P_lo dropped -- consumed by BMODE=1 PV GEMM).
__global__ __launch_bounds__(256) void softmax_rows(float* __restrict__ S) {
  long row = blockIdx.x;
  float* p = S + row * 1024;
  int t = threadIdx.x;
  float4 v = *(float4*)(p + 4 * t);
  float mx = fmaxf(fmaxf(v.x, v.y), fmaxf(v.z, v.w));
#pragma unroll
  for (int i = 1; i < 64; i <<= 1) mx = fmaxf(mx, __shfl_xor(mx, i));
  __shared__ float redm[4];
  __shared__ float reds[4];
  int wave = t >> 6, lane = t & 63;
  if (lane == 0) redm[wave] = mx;
  __syncthreads();
  mx = fmaxf(fmaxf(redm[0], redm[1]), fmaxf(redm[2], redm[3]));
  float e0 = expf(v.x - mx), e1 = expf(v.y - mx);
  float e2 = expf(v.z - mx), e3 = expf(v.w - mx);
  float sum = (e0 + e1) + (e2 + e3);
#pragma unroll
  for (int i = 1; i < 64; i <<= 1) sum += __shfl_xor(sum, i);
  if (lane == 0) reds[wave] = sum;
  __syncthreads();
  sum = (reds[0] + reds[1]) + (reds[2] + reds[3]);
  float inv = 1.0f / sum;
  ushort4_t hv;
  hv.x = bf16_rne(e0 * inv);
  hv.y = bf16_rne(e1 * inv);
  hv.z = bf16_rne(e2 * inv);
  hv.w = bf16_rne(e3 * inv);
  unsigned short* ph = (unsigned short*)p;
  *(ushort4_t*)&ph[4 * t] = hv;
}

}  // namespace

extern "C" void kernel_launch(void* const* d_in, const int* in_sizes, int n_in,
                              void* d_out, int out_size, void* d_ws, size_t ws_size,
                              hipStream_t stream) {
  const float* x  = (const float*)d_in[0];
  const float* qg = (const float*)d_in[1];
  const float* qb = (const float*)d_in[2];
  const float* qm = (const float*)d_in[3];
  const float* qv = (const float*)d_in[4];
  const float* kg = (const float*)d_in[5];
  const float* kb = (const float*)d_in[6];
  const float* km = (const float*)d_in[7];
  const float* kv = (const float*)d_in[8];
  const float* vg = (const float*)d_in[9];
  const float* vb = (const float*)d_in[10];
  const float* vm = (const float*)d_in[11];
  const float* vv = (const float*)d_in[12];
  const float* Wq = (const float*)d_in[13];
  const float* Wk = (const float*)d_in[14];
  const float* Wv = (const float*)d_in[15];
  const float* Wp = (const float*)d_in[16];

  // ---- workspace (r9 layout) ----
  const size_t wFix = 65536 + 16UL * 1024 * 1024;
  const size_t perB = 12UL * 1024 * 1024;
  int G = 32;
  while (G > 1 && wFix + (size_t)G * perB > ws_size) G >>= 1;

  char* ws = (char*)d_ws;
  float* hdr = (float*)ws;

  const long WE = 1024L * 1024;
  unsigned short* WQKh = (unsigned short*)(ws + 65536);  // [2048][1024]
  unsigned short* WQKl = WQKh + 2 * WE;
  unsigned short* Wvh  = WQKl + 2 * WE;
  unsigned short* Wvl  = Wvh + WE;
  unsigned short* Wph  = Wvl + WE;
  unsigned short* Wpl  = Wph + WE;

  const long YB = 524288;
  unsigned short* yqh = Wpl + WE;
  unsigned short* yql = yqh + (long)G * YB;
  unsigned short* ykh = yql + (long)G * YB;
  unsigned short* ykl = ykh + (long)G * YB;
  const long QKBS = 1048576;
  unsigned short* QKh = ykl + (long)G * YB;
  unsigned short* QKl = QKh + (long)G * QKBS;
  float* S = (float*)(QKl + (long)G * QKBS);

  unsigned short* dout_us = (unsigned short*)d_out;

  dim3 blk(256);
  const int BIG = 1 << 30;

  prep3<<<dim3(4), blk, 0, stream>>>(qg, qb, qm, qv, kg, kb, km, kv, vg, vb, vm, vv, hdr);

  const long W4 = WE / 4;
  convert_w<<<dim3(1024), blk, 0, stream>>>(Wq, WQKh, WQKl, W4);
  convert_w<<<dim3(1024), blk, 0, stream>>>(Wk, WQKh + WE, WQKl + WE, W4);
  convert_w<<<dim3(1024), blk, 0, stream>>>(Wv, Wvh, Wvl, W4);
  convert_w<<<dim3(1024), blk, 0, stream>>>(Wp, Wph, Wpl, W4);

  for (int b0 = 0; b0 < Bb; b0 += G) {
    const float* xg = x + (size_t)b0 * Cc * Nn;

    // 1) BN+ReLU+split: yq,yk -> ws; yv -> d_out slots
    convert_y3<<<dim3(2048), blk, 0, stream>>>(
        xg, hdr, yqh, yql, ykh, ykl, dout_us, b0, (long)G * 131072);

    // 2) [Q;K] = [Wq;Wk] x y: M=2048, N=512, K=1024; BM256, m-fastest
    gemm3p<true, true, 256, 0><<<dim3(8 * 2 * G), dim3(512), 0, stream>>>(
        WQKh, WQKl, Nn, 0L,
        yqh, yql, ykh, ykl, 1024, Nn, YB,
        nullptr, QKh, QKl, Cc, QKBS, Nn, 1.0f, 8, 2);

    // 3) S = Q K^T / 32: M=1024, N=1024, K=512; BM256
    gemm3p<false, false, 256, 0><<<dim3(4 * 4 * G), dim3(512), 0, stream>>>(
        QKh, QKl, Cc, QKBS,
        QKh + 524288, QKl + 524288, nullptr, nullptr, BIG, Cc, QKBS,
        S, nullptr, nullptr, Ee, 1048576L, Cc, 0.03125f, 4, 4);

    // 4) softmax rows -> P_hi packed in S (lo dropped)
    softmax_rows<<<dim3(G * Ee), blk, 0, stream>>>(S);

    // 5) Vt[c][e] = sum_n yv[c][n] Wv[e][n]: M=512, N=1024, K=1024; BM128 3-term
    gemm3p<true, false, 128, 0><<<dim3(4 * 4 * G), dim3(512), 0, stream>>>(
        dout_us + (long)b0 * 1048576, dout_us + (long)b0 * 1048576 + 524288, Nn, 1048576L,
        Wvh, Wvl, nullptr, nullptr, BIG, Nn, 0L,
        nullptr, yqh, yql, Ee, YB, Nn, 1.0f, 4, 4);

    // 6) Ot[c][e] = sum_f Vt[c][f] P[e][f]: M=512, N=1024, K=1024; BM128,
    //    B = P_hi only (BMODE=1, 2-term, 64 KiB LDS -> 2 blocks/CU)
    gemm3p<true, false, 128, 1><<<dim3(4 * 4 * G), dim3(512), 0, stream>>>(
        yqh, yql, Ee, YB,
        (unsigned short*)S, nullptr, nullptr, nullptr, BIG,
        2L * Ee, 2097152L,
        nullptr, QKh, QKl, Ee, QKBS, Ee, 1.0f, 4, 4);

    // 7) out[c][n] = sum_e Ot[c][e] Wp[n][e]: M=512, N=1024, K=1024; BM128, f32 out
    gemm3p<false, false, 128, 0><<<dim3(4 * 4 * G), dim3(512), 0, stream>>>(
        QKh, QKl, Ee, QKBS,
        Wph, Wpl, nullptr, nullptr, BIG, Ee, 0L,
        (float*)d_out + (size_t)b0 * Cc * Nn, nullptr, nullptr,
        Nn, (long)Cc * Nn, Ee, 1.0f, 4, 4);
  }
}